// Round 2
// baseline (642.889 us; speedup 1.0000x reference)
//
#include <hip/hip_runtime.h>
#include <hip/hip_bf16.h>

// Problem constants: B=4, T=2048, C=1024, NH=16, HD=64
#define TSEQ   2048
#define CDIM   1024
#define NHEAD  16
#define HDIM   64

typedef float f32x4 __attribute__((ext_vector_type(4)));
typedef __bf16 bf16x8 __attribute__((ext_vector_type(8)));
typedef unsigned short u16x8 __attribute__((ext_vector_type(8)));
typedef unsigned short u16x4 __attribute__((ext_vector_type(4)));

static __device__ __forceinline__ unsigned short f2bf(float f) {
    unsigned u = __builtin_bit_cast(unsigned, f);
    unsigned r = u + 0x7FFFu + ((u >> 16) & 1u);   // round-to-nearest-even
    return (unsigned short)(r >> 16);
}

static __device__ __forceinline__ f32x4 mfma_bf16(u16x8 a, u16x8 b, f32x4 c) {
    return __builtin_amdgcn_mfma_f32_16x16x32_bf16(
        __builtin_bit_cast(bf16x8, a), __builtin_bit_cast(bf16x8, b), c, 0, 0, 0);
}

// Workspace layout (u16 units):
//   wb : 0          .. 4194303   (Wq,Wk,Wv,Wo bf16, 1M each)
//   xb : 4194304    .. 12582911  (x bf16, 8M)   -- reused as `ao` after QKV GEMM
//   qh : 12582912   .. 20971519  ([B,NH,T,HD] bf16)
//   kh : 20971520   .. 29359103
//   vh : 29359104   .. 37748735
// Total 37,748,736 u16 = 75.5 MB.

// ---------------------------------------------------------------------------
// Kernel 1: cast Wq/Wk/Wv/Wo (1M f32 each) then x (8M f32) to bf16 in ws.
// One float4 per thread. 3,145,728 float4 groups = 12288 blocks x 256.
// ---------------------------------------------------------------------------
__global__ __launch_bounds__(256) void cast5(
    const float* __restrict__ x,  const float* __restrict__ wq,
    const float* __restrict__ wk, const float* __restrict__ wv,
    const float* __restrict__ wo, unsigned short* __restrict__ ws)
{
    int t = blockIdx.x * 256 + threadIdx.x;   // float4 index
    const float* src; unsigned short* dst; int off;
    if (t < 2097152)      { src = x;  dst = ws + 4194304; off = t; }
    else if (t < 2359296) { src = wq; dst = ws;           off = t - 2097152; }
    else if (t < 2621440) { src = wk; dst = ws + 1048576; off = t - 2359296; }
    else if (t < 2883584) { src = wv; dst = ws + 2097152; off = t - 2621440; }
    else                  { src = wo; dst = ws + 3145728; off = t - 2883584; }
    f32x4 v = *(const f32x4*)&src[off * 4];
    u16x4 o;
    o[0] = f2bf(v[0]); o[1] = f2bf(v[1]); o[2] = f2bf(v[2]); o[3] = f2bf(v[3]);
    *(u16x4*)&dst[off * 4] = o;
}

// ---------------------------------------------------------------------------
// Kernel 2/4: 128x128 bf16 GEMM, BK=64, 256 threads = 4 waves (2x2 of 64x64).
// A [8192][1024] bf16 row-major, W [1024][1024] bf16 row-major (C = A @ W).
// MODE 0: epilogue writes bf16 head-split [B, NH, T, HD] (z = q/k/v).
// MODE 1: epilogue writes fp32 row-major to d_out.
// ---------------------------------------------------------------------------
template<int MODE>
__global__ __launch_bounds__(256) void gemm128(
    const unsigned short* __restrict__ A, const unsigned short* __restrict__ Wb,
    unsigned short* __restrict__ outb, float* __restrict__ outf)
{
    __shared__ __align__(16) unsigned short Alds[128 * 72];
    __shared__ __align__(16) unsigned short Btl[128 * 72];   // B transposed: [n][k]

    const int tid  = threadIdx.x;
    const int z    = blockIdx.z;
    const int m0   = blockIdx.y * 128;
    const int n0   = blockIdx.x * 128;
    const unsigned short* W = Wb + (MODE == 0 ? z * 1048576 : 0);

    const int wid  = tid >> 6, lane = tid & 63;
    const int wr   = (wid >> 1) * 64, wc = (wid & 1) * 64;
    const int lrow = lane & 15, lk = (lane >> 4) * 8;

    f32x4 acc[4][4] = {};

    for (int kt = 0; kt < 16; ++kt) {           // K = 1024, BK = 64
        __syncthreads();
        // stage A tile 128(m) x 64(k): 1024 x8-loads, row=idx>>3, kchunk=idx&7
        #pragma unroll
        for (int i = 0; i < 4; ++i) {
            int idx = i * 256 + tid;            // 0..1023
            int row = idx >> 3, c8 = idx & 7;
            u16x8 v = *(const u16x8*)&A[(m0 + row) * 1024 + kt * 64 + c8 * 8];
            *(u16x8*)&Alds[row * 72 + c8 * 8] = v;
        }
        // stage B tile 64(k) x 128(n) transposed into Btl[n][k]:
        // 1024 x8-loads, k=idx>>4 (0..63), col-chunk=idx&15 (16 x 8 = 128 cols)
        #pragma unroll
        for (int i = 0; i < 4; ++i) {
            int idx = i * 256 + tid;
            int k = idx >> 4, c8 = idx & 15;
            u16x8 v = *(const u16x8*)&W[(kt * 64 + k) * 1024 + n0 + c8 * 8];
            #pragma unroll
            for (int e = 0; e < 8; ++e)
                Btl[(c8 * 8 + e) * 72 + k] = v[e];
        }
        __syncthreads();
        #pragma unroll
        for (int ks = 0; ks < 2; ++ks) {
            u16x8 af[4], bfr[4];
            #pragma unroll
            for (int m = 0; m < 4; ++m)
                af[m] = *(const u16x8*)&Alds[(wr + m * 16 + lrow) * 72 + ks * 32 + lk];
            #pragma unroll
            for (int n = 0; n < 4; ++n)
                bfr[n] = *(const u16x8*)&Btl[(wc + n * 16 + lrow) * 72 + ks * 32 + lk];
            #pragma unroll
            for (int m = 0; m < 4; ++m)
                #pragma unroll
                for (int n = 0; n < 4; ++n)
                    acc[m][n] = mfma_bf16(af[m], bfr[n], acc[m][n]);
        }
    }

    const int g = lane >> 4;
    #pragma unroll
    for (int m = 0; m < 4; ++m)
        #pragma unroll
        for (int n = 0; n < 4; ++n)
            #pragma unroll
            for (int j = 0; j < 4; ++j) {
                int grow = m0 + wr + m * 16 + g * 4 + j;   // C/D row = (lane>>4)*4+reg
                int gcol = n0 + wc + n * 16 + lrow;        // C/D col = lane&15
                float val = acc[m][n][j];
                if (MODE == 0) {
                    int b = grow >> 11, t = grow & 2047;
                    int h = gcol >> 6,  d = gcol & 63;
                    outb[z * 8388608 + (((b << 4) + h) * 2048 + t) * 64 + d] = f2bf(val);
                } else {
                    outf[grow * 1024 + gcol] = val;
                }
            }
}

// ---------------------------------------------------------------------------
// Kernel 3: flash attention with ALiBi + causal mask.
// Grid (32 q-blocks, 64 b*h). Block = 256 threads = 4 waves; each wave owns
// 16 q-rows; KV tiles of 64 staged in LDS (V transposed for MFMA B-frags).
// ---------------------------------------------------------------------------
__global__ __launch_bounds__(256) void attn_kernel(
    const unsigned short* __restrict__ qh, const unsigned short* __restrict__ kh,
    const unsigned short* __restrict__ vh, unsigned short* __restrict__ aout)
{
    __shared__ __align__(16) unsigned short Klds[64 * 72];
    __shared__ __align__(16) unsigned short Vt[64 * 72];       // V^T: [d][kv]
    __shared__ __align__(16) unsigned short Plds[4 * 16 * 72]; // per-wave P

    const int blk = blockIdx.x;            // q-block (64 rows)
    const int bh  = blockIdx.y;            // b*16 + h
    const int h   = bh & 15, b = bh >> 4;
    const int tid = threadIdx.x, wid = tid >> 6, lane = tid & 63;
    const int q0  = blk * 64;
    const int lrow = lane & 15, g = lane >> 4, lk = g * 8;

    const unsigned short* Qb = qh + bh * (TSEQ * HDIM);
    const unsigned short* Kb = kh + bh * (TSEQ * HDIM);
    const unsigned short* Vb = vh + bh * (TSEQ * HDIM);

    // Q fragments live in registers: row = lane&15, k(=d) = (lane>>4)*8+i
    const int qrow = q0 + wid * 16 + lrow;
    u16x8 qf[2];
    qf[0] = *(const u16x8*)&Qb[qrow * 64 + 0 + lk];
    qf[1] = *(const u16x8*)&Qb[qrow * 64 + 32 + lk];

    const float slope = exp2f(-0.5f * (float)(h + 1));  // ALiBi slopes, nh=16
    float m_r[4] = {-1e30f, -1e30f, -1e30f, -1e30f};
    float l_r[4] = {};
    f32x4 Oa[4] = {};

    const int ntiles = blk + 1;            // causal: kv tiles 0..blk
    for (int kt = 0; kt < ntiles; ++kt) {
        const int kv0 = kt * 64;
        __syncthreads();
        // stage K [64][64] and V^T [64][64]
        #pragma unroll
        for (int i = 0; i < 2; ++i) {
            int idx = i * 256 + tid;       // 0..511
            int row = idx >> 3, c8 = idx & 7;
            u16x8 kv = *(const u16x8*)&Kb[(kv0 + row) * 64 + c8 * 8];
            *(u16x8*)&Klds[row * 72 + c8 * 8] = kv;
            u16x8 vv = *(const u16x8*)&Vb[(kv0 + row) * 64 + c8 * 8];
            #pragma unroll
            for (int e = 0; e < 8; ++e)
                Vt[(c8 * 8 + e) * 72 + row] = vv[e];
        }
        __syncthreads();

        // S = Q K^T : 4 col-frags (16 kv each) x 2 k-steps
        f32x4 s[4];
        #pragma unroll
        for (int n = 0; n < 4; ++n) {
            f32x4 a = {};
            #pragma unroll
            for (int ks = 0; ks < 2; ++ks) {
                u16x8 bfr = *(const u16x8*)&Klds[(n * 16 + lrow) * 72 + ks * 32 + lk];
                a = mfma_bf16(qf[ks], bfr, a);
            }
            s[n] = a;
        }

        // scale + ALiBi bias + causal mask (only diagonal tile needs mask)
        const bool diag = (kt == blk);
        float sc[4][4];
        #pragma unroll
        for (int n = 0; n < 4; ++n) {
            int kvg = kv0 + n * 16 + lrow;
            float bias = slope * ((float)kvg - 2047.0f);
            #pragma unroll
            for (int j = 0; j < 4; ++j) {
                float v = s[n][j] * 0.125f + bias;
                int qg = q0 + wid * 16 + g * 4 + j;
                if (diag && kvg > qg) v = -1e30f;
                sc[n][j] = v;
            }
        }

        // online softmax: row reductions across the 16-lane group
        float alpha[4];
        #pragma unroll
        for (int j = 0; j < 4; ++j) {
            float rm = fmaxf(fmaxf(sc[0][j], sc[1][j]), fmaxf(sc[2][j], sc[3][j]));
            #pragma unroll
            for (int off = 1; off < 16; off <<= 1)
                rm = fmaxf(rm, __shfl_xor(rm, off, 64));
            float mn = fmaxf(m_r[j], rm);
            alpha[j] = __expf(m_r[j] - mn);
            m_r[j] = mn;
        }
        #pragma unroll
        for (int j = 0; j < 4; ++j) {
            float rs = 0.f;
            #pragma unroll
            for (int n = 0; n < 4; ++n) {
                float p = __expf(sc[n][j] - m_r[j]);
                sc[n][j] = p;
                rs += p;
            }
            #pragma unroll
            for (int off = 1; off < 16; off <<= 1)
                rs += __shfl_xor(rs, off, 64);
            l_r[j] = l_r[j] * alpha[j] + rs;
        }
        #pragma unroll
        for (int dn = 0; dn < 4; ++dn)
            #pragma unroll
            for (int j = 0; j < 4; ++j)
                Oa[dn][j] *= alpha[j];

        // write P (bf16) to this wave's private LDS region, C-layout -> row-major
        unsigned short* Pw = &Plds[wid * 16 * 72];
        #pragma unroll
        for (int n = 0; n < 4; ++n)
            #pragma unroll
            for (int j = 0; j < 4; ++j)
                Pw[(g * 4 + j) * 72 + n * 16 + lrow] = f2bf(sc[n][j]);

        // O += P @ V : A-frag from Plds (row-major), B-frag from Vt
        #pragma unroll
        for (int dn = 0; dn < 4; ++dn) {
            f32x4 a = Oa[dn];
            #pragma unroll
            for (int ks = 0; ks < 2; ++ks) {
                u16x8 pa = *(const u16x8*)&Pw[lrow * 72 + ks * 32 + lk];
                u16x8 vb = *(const u16x8*)&Vt[(dn * 16 + lrow) * 72 + ks * 32 + lk];
                a = mfma_bf16(pa, vb, a);
            }
            Oa[dn] = a;
        }
    }

    // epilogue: normalize and write bf16 to [B*T][C] (head-concat layout)
    #pragma unroll
    for (int dn = 0; dn < 4; ++dn)
        #pragma unroll
        for (int j = 0; j < 4; ++j) {
            int qg = q0 + wid * 16 + g * 4 + j;
            float val = Oa[dn][j] / l_r[j];
            aout[(b * 2048 + qg) * 1024 + h * 64 + dn * 16 + lrow] = f2bf(val);
        }
}

// ---------------------------------------------------------------------------
extern "C" void kernel_launch(void* const* d_in, const int* in_sizes, int n_in,
                              void* d_out, int out_size, void* d_ws, size_t ws_size,
                              hipStream_t stream)
{
    const float* x  = (const float*)d_in[0];
    const float* Wq = (const float*)d_in[1];
    const float* Wk = (const float*)d_in[2];
    const float* Wv = (const float*)d_in[3];
    const float* Wo = (const float*)d_in[4];

    unsigned short* ws = (unsigned short*)d_ws;
    unsigned short* wb = ws;                       // 4 x 1M bf16 (q,k,v,o)
    unsigned short* xb = ws + 4194304;             // 8M bf16
    unsigned short* qh = ws + 12582912;            // [B,NH,T,HD] bf16
    unsigned short* kh = qh + 8388608;
    unsigned short* vh = kh + 8388608;
    unsigned short* ao = xb;                       // alias: xb dead after QKV GEMM

    cast5<<<dim3(12288), dim3(256), 0, stream>>>(x, Wq, Wk, Wv, Wo, ws);
    gemm128<0><<<dim3(8, 64, 3), dim3(256), 0, stream>>>(xb, wb, qh, (float*)nullptr);
    attn_kernel<<<dim3(32, 64), dim3(256), 0, stream>>>(qh, kh, vh, ao);
    gemm128<1><<<dim3(8, 64, 1), dim3(256), 0, stream>>>(
        ao, wb + 3 * 1048576, (unsigned short*)nullptr, (float*)d_out);
}

// Round 3
// 549.472 us; speedup vs baseline: 1.1700x; 1.1700x over previous
//
#include <hip/hip_runtime.h>
#include <hip/hip_bf16.h>

// Problem constants: B=4, T=2048, C=1024, NH=16, HD=64
#define TSEQ   2048
#define CDIM   1024
#define NHEAD  16
#define HDIM   64

typedef float f32x4 __attribute__((ext_vector_type(4)));
typedef __bf16 bf16x8 __attribute__((ext_vector_type(8)));
typedef unsigned short u16x8 __attribute__((ext_vector_type(8)));
typedef unsigned short u16x4 __attribute__((ext_vector_type(4)));

static __device__ __forceinline__ unsigned short f2bf(float f) {
    unsigned u = __builtin_bit_cast(unsigned, f);
    unsigned r = u + 0x7FFFu + ((u >> 16) & 1u);   // round-to-nearest-even
    return (unsigned short)(r >> 16);
}

static __device__ __forceinline__ f32x4 mfma_bf16(u16x8 a, u16x8 b, f32x4 c) {
    return __builtin_amdgcn_mfma_f32_16x16x32_bf16(
        __builtin_bit_cast(bf16x8, a), __builtin_bit_cast(bf16x8, b), c, 0, 0, 0);
}

// Workspace layout (u16 units):
//   wb : 0          .. 4194303   (Wq,Wk,Wv,Wo bf16, 1M each)
//   xb : 4194304    .. 12582911  (x bf16, 8M)   -- reused as `ao` after QKV GEMM
//   qh : 12582912   .. 20971519  ([B,NH,T,HD] bf16)
//   kh : 20971520   .. 29359103  ([B,NH,T,HD] bf16)
//   vt : 29359104   .. 37748735  ([B,NH,HD,T] bf16 -- V TRANSPOSED)

// ---------------------------------------------------------------------------
// Kernel 1: cast Wq/Wk/Wv/Wo (1M f32 each) and x (8M f32) to bf16 in ws.
// ---------------------------------------------------------------------------
__global__ __launch_bounds__(256) void cast5(
    const float* __restrict__ x,  const float* __restrict__ wq,
    const float* __restrict__ wk, const float* __restrict__ wv,
    const float* __restrict__ wo, unsigned short* __restrict__ ws)
{
    int t = blockIdx.x * 256 + threadIdx.x;   // float4 index
    const float* src; unsigned short* dst; int off;
    if (t < 2097152)      { src = x;  dst = ws + 4194304; off = t; }
    else if (t < 2359296) { src = wq; dst = ws;           off = t - 2097152; }
    else if (t < 2621440) { src = wk; dst = ws + 1048576; off = t - 2359296; }
    else if (t < 2883584) { src = wv; dst = ws + 2097152; off = t - 2621440; }
    else                  { src = wo; dst = ws + 3145728; off = t - 2883584; }
    f32x4 v = *(const f32x4*)&src[off * 4];
    u16x4 o;
    o[0] = f2bf(v[0]); o[1] = f2bf(v[1]); o[2] = f2bf(v[2]); o[3] = f2bf(v[3]);
    *(u16x4*)&dst[off * 4] = o;
}

// ---------------------------------------------------------------------------
// Kernel 2/4: 128x128 bf16 GEMM, BK=64, 256 threads = 4 waves (2x2 of 64x64).
// MODE 0: z = q/k/v. q,k write head-split [B,NH,T,HD]; v writes TRANSPOSED
//         [B,NH,HD,T] so attention can stage V^T with vector loads.
// MODE 1: epilogue writes fp32 row-major to d_out.
// ---------------------------------------------------------------------------
template<int MODE>
__global__ __launch_bounds__(256) void gemm128(
    const unsigned short* __restrict__ A, const unsigned short* __restrict__ Wb,
    unsigned short* __restrict__ outb, float* __restrict__ outf)
{
    __shared__ __align__(16) unsigned short Alds[128 * 72];
    __shared__ __align__(16) unsigned short Btl[128 * 72];   // B transposed: [n][k]

    const int tid  = threadIdx.x;
    const int z    = blockIdx.z;
    const int m0   = blockIdx.y * 128;
    const int n0   = blockIdx.x * 128;
    const unsigned short* W = Wb + (MODE == 0 ? z * 1048576 : 0);

    const int wid  = tid >> 6, lane = tid & 63;
    const int wr   = (wid >> 1) * 64, wc = (wid & 1) * 64;
    const int lrow = lane & 15, lk = (lane >> 4) * 8;

    f32x4 acc[4][4] = {};

    for (int kt = 0; kt < 16; ++kt) {           // K = 1024, BK = 64
        __syncthreads();
        // stage A tile 128(m) x 64(k)
        #pragma unroll
        for (int i = 0; i < 4; ++i) {
            int idx = i * 256 + tid;            // 0..1023
            int row = idx >> 3, c8 = idx & 7;
            u16x8 v = *(const u16x8*)&A[(m0 + row) * 1024 + kt * 64 + c8 * 8];
            *(u16x8*)&Alds[row * 72 + c8 * 8] = v;
        }
        // stage B tile 64(k) x 128(n) transposed into Btl[n][k]
        #pragma unroll
        for (int i = 0; i < 4; ++i) {
            int idx = i * 256 + tid;
            int k = idx >> 4, c8 = idx & 15;
            u16x8 v = *(const u16x8*)&W[(kt * 64 + k) * 1024 + n0 + c8 * 8];
            #pragma unroll
            for (int e = 0; e < 8; ++e)
                Btl[(c8 * 8 + e) * 72 + k] = v[e];
        }
        __syncthreads();
        #pragma unroll
        for (int ks = 0; ks < 2; ++ks) {
            u16x8 af[4], bfr[4];
            #pragma unroll
            for (int m = 0; m < 4; ++m)
                af[m] = *(const u16x8*)&Alds[(wr + m * 16 + lrow) * 72 + ks * 32 + lk];
            #pragma unroll
            for (int n = 0; n < 4; ++n)
                bfr[n] = *(const u16x8*)&Btl[(wc + n * 16 + lrow) * 72 + ks * 32 + lk];
            #pragma unroll
            for (int m = 0; m < 4; ++m)
                #pragma unroll
                for (int n = 0; n < 4; ++n)
                    acc[m][n] = mfma_bf16(af[m], bfr[n], acc[m][n]);
        }
    }

    const int g = lane >> 4;
    #pragma unroll
    for (int m = 0; m < 4; ++m)
        #pragma unroll
        for (int n = 0; n < 4; ++n)
            #pragma unroll
            for (int j = 0; j < 4; ++j) {
                int grow = m0 + wr + m * 16 + g * 4 + j;   // C/D row = (lane>>4)*4+reg
                int gcol = n0 + wc + n * 16 + lrow;        // C/D col = lane&15
                float val = acc[m][n][j];
                if (MODE == 0) {
                    int b = grow >> 11, t = grow & 2047;
                    int h = gcol >> 6,  d = gcol & 63;
                    if (z == 2)   // V: store transposed [bh][d][t]
                        outb[z * 8388608 + (((b << 4) + h) * 64 + d) * 2048 + t] = f2bf(val);
                    else
                        outb[z * 8388608 + (((b << 4) + h) * 2048 + t) * 64 + d] = f2bf(val);
                } else {
                    outf[grow * 1024 + gcol] = val;
                }
            }
}

// ---------------------------------------------------------------------------
// Kernel 3: flash attention with ALiBi + causal mask.
// Grid (16 q-blocks, 64 b*h). Block = 256 = 4 waves; each wave owns 32 q-rows
// (2 row-frags). KV tiles of 64; K and V^T staged in LDS with b128 writes.
// ---------------------------------------------------------------------------
__global__ __launch_bounds__(256) void attn_kernel(
    const unsigned short* __restrict__ qh, const unsigned short* __restrict__ kh,
    const unsigned short* __restrict__ vt, unsigned short* __restrict__ aout)
{
    __shared__ __align__(16) unsigned short Klds[64 * 72];
    __shared__ __align__(16) unsigned short Vlds[64 * 72];     // V^T tile: [d][kv]
    __shared__ __align__(16) unsigned short Plds[4 * 32 * 72]; // per-wave P (32 rows)

    const int blk = 15 - blockIdx.x;       // largest q-blocks dispatch first
    const int bh  = blockIdx.y;            // b*16 + h
    const int h   = bh & 15, b = bh >> 4;
    const int tid = threadIdx.x, wid = tid >> 6, lane = tid & 63;
    const int q0  = blk * 128;
    const int lrow = lane & 15, g = lane >> 4, lk = g * 8;

    const unsigned short* Qb = qh + bh * (TSEQ * HDIM);
    const unsigned short* Kb = kh + bh * (TSEQ * HDIM);
    const unsigned short* Vb = vt + bh * (TSEQ * HDIM);  // [d][t]

    const int qw = q0 + wid * 32;          // this wave's first q row

    // Q fragments in registers: A-frag row = lane&15, k(=d) = (lane>>4)*8+i
    u16x8 qf[2][2];
    #pragma unroll
    for (int m = 0; m < 2; ++m)
        #pragma unroll
        for (int ks = 0; ks < 2; ++ks)
            qf[m][ks] = *(const u16x8*)&Qb[(qw + m * 16 + lrow) * 64 + ks * 32 + lk];

    const float slope = exp2f(-0.5f * (float)(h + 1));  // ALiBi slopes, nh=16
    float m_r[2][4], l_r[2][4] = {};
    f32x4 Oa[2][4] = {};
    #pragma unroll
    for (int m = 0; m < 2; ++m)
        #pragma unroll
        for (int j = 0; j < 4; ++j) m_r[m][j] = -1e30f;

    unsigned short* Pw = &Plds[wid * 32 * 72];

    const int ntiles = 2 * blk + 2;        // causal: kv tiles 0..2blk+1
    for (int kt = 0; kt < ntiles; ++kt) {
        const int kv0 = kt * 64;
        __syncthreads();
        // stage K [64 kv][64 d] and V^T [64 d][64 kv], both vectorized
        #pragma unroll
        for (int i = 0; i < 2; ++i) {
            int idx = i * 256 + tid;       // 0..511
            int row = idx >> 3, c8 = idx & 7;
            *(u16x8*)&Klds[row * 72 + c8 * 8] =
                *(const u16x8*)&Kb[(kv0 + row) * 64 + c8 * 8];
            *(u16x8*)&Vlds[row * 72 + c8 * 8] =
                *(const u16x8*)&Vb[row * 2048 + kv0 + c8 * 8];
        }
        __syncthreads();
        if (kv0 > qw + 31) continue;       // fully masked for this wave (uniform)

        // K frags (shared across both q row-frags)
        u16x8 kf[4][2];
        #pragma unroll
        for (int n = 0; n < 4; ++n)
            #pragma unroll
            for (int ks = 0; ks < 2; ++ks)
                kf[n][ks] = *(const u16x8*)&Klds[(n * 16 + lrow) * 72 + ks * 32 + lk];

        // S = Q K^T
        f32x4 s[2][4];
        #pragma unroll
        for (int m = 0; m < 2; ++m)
            #pragma unroll
            for (int n = 0; n < 4; ++n) {
                f32x4 a = {};
                a = mfma_bf16(qf[m][0], kf[n][0], a);
                a = mfma_bf16(qf[m][1], kf[n][1], a);
                s[m][n] = a;
            }

        const bool diag = (kv0 + 63 > qw);  // any masking possible in this tile
        float sc[2][4][4];
        #pragma unroll
        for (int m = 0; m < 2; ++m)
            #pragma unroll
            for (int n = 0; n < 4; ++n) {
                int kvg = kv0 + n * 16 + lrow;
                float bias = slope * ((float)kvg - 2047.0f);
                #pragma unroll
                for (int j = 0; j < 4; ++j) {
                    float v = s[m][n][j] * 0.125f + bias;
                    int qg = qw + m * 16 + g * 4 + j;
                    if (diag && kvg > qg) v = -1e30f;
                    sc[m][n][j] = v;
                }
            }

        // online softmax: reduce over n (in-lane) + 16-lane group (shfl)
        #pragma unroll
        for (int m = 0; m < 2; ++m) {
            float alpha[4];
            #pragma unroll
            for (int j = 0; j < 4; ++j) {
                float rm = fmaxf(fmaxf(sc[m][0][j], sc[m][1][j]),
                                 fmaxf(sc[m][2][j], sc[m][3][j]));
                #pragma unroll
                for (int off = 1; off < 16; off <<= 1)
                    rm = fmaxf(rm, __shfl_xor(rm, off, 64));
                float mn = fmaxf(m_r[m][j], rm);
                alpha[j] = __expf(m_r[m][j] - mn);
                m_r[m][j] = mn;
            }
            #pragma unroll
            for (int j = 0; j < 4; ++j) {
                float rs = 0.f;
                #pragma unroll
                for (int n = 0; n < 4; ++n) {
                    float p = __expf(sc[m][n][j] - m_r[m][j]);
                    sc[m][n][j] = p;
                    rs += p;
                }
                #pragma unroll
                for (int off = 1; off < 16; off <<= 1)
                    rs += __shfl_xor(rs, off, 64);
                l_r[m][j] = l_r[m][j] * alpha[j] + rs;
            }
            #pragma unroll
            for (int dn = 0; dn < 4; ++dn)
                #pragma unroll
                for (int j = 0; j < 4; ++j)
                    Oa[m][dn][j] *= alpha[j];

            // write P rows (wave-private region, no barrier needed)
            #pragma unroll
            for (int n = 0; n < 4; ++n)
                #pragma unroll
                for (int j = 0; j < 4; ++j)
                    Pw[(m * 16 + g * 4 + j) * 72 + n * 16 + lrow] = f2bf(sc[m][n][j]);
        }

        // V^T frags (shared across both q row-frags)
        u16x8 vb[4][2];
        #pragma unroll
        for (int dn = 0; dn < 4; ++dn)
            #pragma unroll
            for (int ks = 0; ks < 2; ++ks)
                vb[dn][ks] = *(const u16x8*)&Vlds[(dn * 16 + lrow) * 72 + ks * 32 + lk];

        // O += P @ V
        #pragma unroll
        for (int m = 0; m < 2; ++m) {
            u16x8 pa[2];
            pa[0] = *(const u16x8*)&Pw[(m * 16 + lrow) * 72 + 0 + lk];
            pa[1] = *(const u16x8*)&Pw[(m * 16 + lrow) * 72 + 32 + lk];
            #pragma unroll
            for (int dn = 0; dn < 4; ++dn) {
                f32x4 a = Oa[m][dn];
                a = mfma_bf16(pa[0], vb[dn][0], a);
                a = mfma_bf16(pa[1], vb[dn][1], a);
                Oa[m][dn] = a;
            }
        }
    }

    // epilogue: normalize, write bf16 to [B*T][C] (head-concat layout)
    #pragma unroll
    for (int m = 0; m < 2; ++m)
        #pragma unroll
        for (int dn = 0; dn < 4; ++dn)
            #pragma unroll
            for (int j = 0; j < 4; ++j) {
                int qg = qw + m * 16 + g * 4 + j;
                float val = Oa[m][dn][j] / l_r[m][j];
                aout[(b * 2048 + qg) * 1024 + h * 64 + dn * 16 + lrow] = f2bf(val);
            }
}

// ---------------------------------------------------------------------------
extern "C" void kernel_launch(void* const* d_in, const int* in_sizes, int n_in,
                              void* d_out, int out_size, void* d_ws, size_t ws_size,
                              hipStream_t stream)
{
    const float* x  = (const float*)d_in[0];
    const float* Wq = (const float*)d_in[1];
    const float* Wk = (const float*)d_in[2];
    const float* Wv = (const float*)d_in[3];
    const float* Wo = (const float*)d_in[4];

    unsigned short* ws = (unsigned short*)d_ws;
    unsigned short* wb = ws;                       // 4 x 1M bf16 (q,k,v,o)
    unsigned short* xb = ws + 4194304;             // 8M bf16
    unsigned short* qh = ws + 12582912;            // [B,NH,T,HD] bf16
    unsigned short* kh = qh + 8388608;
    unsigned short* vt = kh + 8388608;             // [B,NH,HD,T] bf16 (transposed)
    unsigned short* ao = xb;                       // alias: xb dead after QKV GEMM

    cast5<<<dim3(12288), dim3(256), 0, stream>>>(x, Wq, Wk, Wv, Wo, ws);
    gemm128<0><<<dim3(8, 64, 3), dim3(256), 0, stream>>>(xb, wb, qh, (float*)nullptr);
    attn_kernel<<<dim3(16, 64), dim3(256), 0, stream>>>(qh, kh, vt, ao);
    gemm128<1><<<dim3(8, 64, 1), dim3(256), 0, stream>>>(
        ao, wb + 3 * 1048576, (unsigned short*)nullptr, (float*)d_out);
}

// Round 4
// 309.945 us; speedup vs baseline: 2.0742x; 1.7728x over previous
//
#include <hip/hip_runtime.h>
#include <hip/hip_bf16.h>

// Problem constants: B=4, T=2048, C=1024, NH=16, HD=64
#define TSEQ   2048
#define CDIM   1024
#define NHEAD  16
#define HDIM   64

typedef float f32x4  __attribute__((ext_vector_type(4)));
typedef float f32x16v __attribute__((ext_vector_type(16)));
typedef __bf16 bf16x8 __attribute__((ext_vector_type(8)));
typedef unsigned short u16x8 __attribute__((ext_vector_type(8)));
typedef unsigned short u16x4 __attribute__((ext_vector_type(4)));
typedef unsigned int   u32x4 __attribute__((ext_vector_type(4)));

#define QSCALE 0.18033688011112042f   // 0.125 * log2(e)
#define LOG2E  1.4426950408889634f

static __device__ __forceinline__ unsigned short f2bf(float f) {
    unsigned u = __builtin_bit_cast(unsigned, f);
    unsigned r = u + 0x7FFFu + ((u >> 16) & 1u);   // round-to-nearest-even
    return (unsigned short)(r >> 16);
}

static __device__ __forceinline__ f32x4 mfma16(u16x8 a, u16x8 b, f32x4 c) {
    return __builtin_amdgcn_mfma_f32_16x16x32_bf16(
        __builtin_bit_cast(bf16x8, a), __builtin_bit_cast(bf16x8, b), c, 0, 0, 0);
}
static __device__ __forceinline__ f32x16v mfma32(u16x8 a, u16x8 b, f32x16v c) {
    return __builtin_amdgcn_mfma_f32_32x32x16_bf16(
        __builtin_bit_cast(bf16x8, a), __builtin_bit_cast(bf16x8, b), c, 0, 0, 0);
}

static __device__ __forceinline__ void gload16(const void* g, void* l) {
    __builtin_amdgcn_global_load_lds(
        (const __attribute__((address_space(1))) unsigned int*)g,
        (__attribute__((address_space(3))) unsigned int*)l, 16, 0, 0);
}

// Workspace layout (u16 units):
//   wb : 0          .. 4194303   (W^T q,k,v,o bf16, 1M each -- TRANSPOSED [n][k])
//   xb : 4194304    .. 12582911  (x bf16, 8M)  -- reused as `ao` after QKV GEMM
//   qh : 12582912   .. 20971519  ([B,NH,T,HD] bf16, pre-scaled by QSCALE)
//   kh : 20971520   .. 29359103  ([B,NH,T,HD] bf16)
//   vt : 29359104   .. 37748735  ([B,NH,HD,T] bf16 -- V TRANSPOSED)

// ---------------------------------------------------------------------------
// Kernel 1a: cast x (8M f32) to bf16.
// ---------------------------------------------------------------------------
__global__ __launch_bounds__(256) void castx(
    const float* __restrict__ x, unsigned short* __restrict__ xb)
{
    int t = blockIdx.x * 256 + threadIdx.x;   // float4 index, < 2097152
    f32x4 v = *(const f32x4*)&x[t * 4];
    u16x4 o;
    o[0] = f2bf(v[0]); o[1] = f2bf(v[1]); o[2] = f2bf(v[2]); o[3] = f2bf(v[3]);
    *(u16x4*)&xb[t * 4] = o;
}

// ---------------------------------------------------------------------------
// Kernel 1b: transpose+cast the 4 weights: W [k][n] f32 -> W^T [n][k] bf16.
// Grid (16,16,4), 64x64 tiles via LDS.
// ---------------------------------------------------------------------------
__global__ __launch_bounds__(256) void wtcast(
    const float* __restrict__ wq, const float* __restrict__ wk,
    const float* __restrict__ wv, const float* __restrict__ wo,
    unsigned short* __restrict__ wt)
{
    __shared__ unsigned short t[64 * 72];
    const int z = blockIdx.z;
    const float* src = (z == 0) ? wq : (z == 1) ? wk : (z == 2) ? wv : wo;
    const int k0 = blockIdx.x * 64, n0 = blockIdx.y * 64, tid = threadIdx.x;

    #pragma unroll
    for (int i = 0; i < 4; ++i) {
        int idx = i * 256 + tid;           // 0..1023
        int r = idx >> 4, c4 = idx & 15;   // r = k-row, c4 = 4-col chunk
        f32x4 v = *(const f32x4*)&src[(k0 + r) * 1024 + n0 + c4 * 4];
        u16x4 o;
        o[0] = f2bf(v[0]); o[1] = f2bf(v[1]); o[2] = f2bf(v[2]); o[3] = f2bf(v[3]);
        *(u16x4*)&t[r * 72 + c4 * 4] = o;
    }
    __syncthreads();
    #pragma unroll
    for (int i = 0; i < 2; ++i) {
        int idx = i * 256 + tid;           // 0..511
        int n = idx >> 3, k8 = idx & 7;
        u16x8 o;
        #pragma unroll
        for (int e = 0; e < 8; ++e) o[e] = t[(k8 * 8 + e) * 72 + n];
        *(u16x8*)&wt[z * 1048576 + (n0 + n) * 1024 + k0 + k8 * 8] = o;
    }
}

// ---------------------------------------------------------------------------
// Kernel 2/4: 128x128 bf16 GEMM, BK=64, m97-style global_load_lds staging.
// A [8192][1024] row-major; WT [n][k] (pre-transposed). 4 waves (2x2 of 64x64).
// MODE 0: z = q/k/v. q scaled by QSCALE; v written transposed [bh][d][t].
// MODE 1: fp32 row-major to d_out.
// ---------------------------------------------------------------------------
template<int MODE>
__global__ __launch_bounds__(256) void gemm_gl(
    const unsigned short* __restrict__ A, const unsigned short* __restrict__ WT,
    unsigned short* __restrict__ outb, float* __restrict__ outf)
{
    __shared__ __align__(16) unsigned short Al[128 * 64];
    __shared__ __align__(16) unsigned short Bl[128 * 64];   // B^T tile: [n][k]

    const int tid  = threadIdx.x;
    const int z    = blockIdx.z;
    const int m0   = blockIdx.y * 128;
    const int n0   = blockIdx.x * 128;
    const unsigned short* W = WT + (MODE == 0 ? z * 1048576 : 0);

    const int wid  = tid >> 6, lane = tid & 63;
    const int wr   = (wid >> 1) * 64, wc = (wid & 1) * 64;
    const int lrow = lane & 15, lk = (lane >> 4) * 8;

    f32x4 acc[4][4] = {};

    for (int kt = 0; kt < 16; ++kt) {           // K = 1024, BK = 64
        __syncthreads();
        // stage A and B^T tiles: 16 chunks each, chunk = 8 rows x 64 cols (1KB)
        #pragma unroll
        for (int c = 0; c < 4; ++c) {
            int cz = wid * 4 + c;                       // 0..15
            int row = cz * 8 + (lane >> 3), col = (lane & 7) * 8;
            gload16(&A[(m0 + row) * 1024 + kt * 64 + col], &Al[cz * 512]);
            gload16(&W[(n0 + row) * 1024 + kt * 64 + col], &Bl[cz * 512]);
        }
        __syncthreads();
        #pragma unroll
        for (int ks = 0; ks < 2; ++ks) {
            u16x8 af[4], bfr[4];
            #pragma unroll
            for (int m = 0; m < 4; ++m)
                af[m] = *(const u16x8*)&Al[(wr + m * 16 + lrow) * 64 + ks * 32 + lk];
            #pragma unroll
            for (int n = 0; n < 4; ++n)
                bfr[n] = *(const u16x8*)&Bl[(wc + n * 16 + lrow) * 64 + ks * 32 + lk];
            #pragma unroll
            for (int m = 0; m < 4; ++m)
                #pragma unroll
                for (int n = 0; n < 4; ++n)
                    acc[m][n] = mfma16(af[m], bfr[n], acc[m][n]);
        }
    }

    const int g = lane >> 4;
    #pragma unroll
    for (int m = 0; m < 4; ++m)
        #pragma unroll
        for (int n = 0; n < 4; ++n)
            #pragma unroll
            for (int j = 0; j < 4; ++j) {
                int grow = m0 + wr + m * 16 + g * 4 + j;   // C/D row
                int gcol = n0 + wc + n * 16 + lrow;        // C/D col
                float val = acc[m][n][j];
                if (MODE == 0) {
                    int b = grow >> 11, t = grow & 2047;
                    int h = gcol >> 6,  d = gcol & 63;
                    if (z == 0) val *= QSCALE;             // fold attn scale into Q
                    if (z == 2)   // V: store transposed [bh][d][t]
                        outb[z * 8388608 + (((b << 4) + h) * 64 + d) * 2048 + t] = f2bf(val);
                    else
                        outb[z * 8388608 + (((b << 4) + h) * 2048 + t) * 64 + d] = f2bf(val);
                } else {
                    outf[grow * 1024 + gcol] = val;
                }
            }
}

// ---------------------------------------------------------------------------
// Kernel 3: flash attention, 32x32 MFMA, swapped QK^T (S^T = K.Q), in-register
// softmax (1 q-row per lane), P kept in registers (shfl half-exchange).
// Grid (16 q-blocks of 128, 64 b*h). 256 thr = 4 waves x 32 q-rows.
// ---------------------------------------------------------------------------
__global__ __launch_bounds__(256) void attn32(
    const unsigned short* __restrict__ qh, const unsigned short* __restrict__ kh,
    const unsigned short* __restrict__ vt, unsigned short* __restrict__ aout)
{
    __shared__ __align__(16) unsigned short Klds[64 * 72];
    __shared__ __align__(16) unsigned short Vlds[64 * 72];   // V^T tile: [d][kv]

    const int blk = 15 - blockIdx.x;       // largest q-blocks first
    const int bh  = blockIdx.y;
    const int h   = bh & 15, b = bh >> 4;
    const int tid = threadIdx.x, wid = tid >> 6, lane = tid & 63;
    const int l31 = lane & 31, hi = lane >> 5;
    const int q0  = blk * 128;
    const int qw  = q0 + wid * 32;         // wave's first q row

    const unsigned short* Qb = qh + bh * (TSEQ * HDIM);
    const unsigned short* Kb = kh + bh * (TSEQ * HDIM);
    const unsigned short* Vb = vt + bh * (TSEQ * HDIM);  // [d][t]

    const int qg = qw + l31;               // this lane's q row
    // Q B-frags: col=l31 -> q, k = kf*16 + hi*8 + i  (Q pre-scaled by QSCALE)
    u16x8 qf[4];
    #pragma unroll
    for (int kf = 0; kf < 4; ++kf)
        qf[kf] = *(const u16x8*)&Qb[qg * 64 + kf * 16 + hi * 8];

    const float slope2 = exp2f(-0.5f * (float)(h + 1)) * LOG2E;
    float m_r = -1e30f, l_r = 0.f;
    f32x16v Ot[2] = {};                    // O^T: d = dn*32+(r&3)+8*(r>>2)+4*hi, q = l31

    const int ntiles = 2 * blk + 2;
    for (int kt = 0; kt < ntiles; ++kt) {
        const int kv0 = kt * 64;
        __syncthreads();
        #pragma unroll
        for (int i = 0; i < 2; ++i) {
            int idx = i * 256 + tid;       // 0..511
            int row = idx >> 3, c8 = idx & 7;
            *(u16x8*)&Klds[row * 72 + c8 * 8] =
                *(const u16x8*)&Kb[(kv0 + row) * 64 + c8 * 8];
            *(u16x8*)&Vlds[row * 72 + c8 * 8] =
                *(const u16x8*)&Vb[row * 2048 + kv0 + c8 * 8];
        }
        __syncthreads();
        if (kv0 > qw + 31) continue;       // fully masked for this wave

        // S^T = K . Q : A = K rows (kv), B = Q cols (q). 2 kv-frags x 4 k-frags.
        f32x16v st[2];
        #pragma unroll
        for (int kv2 = 0; kv2 < 2; ++kv2) {
            f32x16v a = {};
            #pragma unroll
            for (int kf = 0; kf < 4; ++kf) {
                u16x8 ka = *(const u16x8*)&Klds[(kv2 * 32 + l31) * 72 + kf * 16 + hi * 8];
                a = mfma32(ka, qf[kf], a);
            }
            st[kv2] = a;
        }

        // bias (+ causal mask on diagonal tiles); all in exp2 domain
        const bool diag = (kv0 + 63 > qw);
        #pragma unroll
        for (int kv2 = 0; kv2 < 2; ++kv2) {
            float base = slope2 * (float)(kv0 + kv2 * 32 + 4 * hi - 2047);
            #pragma unroll
            for (int r = 0; r < 16; ++r) {
                int koff = (r & 3) + 8 * (r >> 2);       // + 4*hi in base
                float v = st[kv2][r] + fmaf(slope2, (float)koff, base);
                if (diag) {
                    int kv = kv0 + kv2 * 32 + koff + 4 * hi;
                    if (kv > qg) v = -1e30f;
                }
                st[kv2][r] = v;
            }
        }

        // row max: in-lane tree over 32 + one cross-half swap
        float t8[8];
        #pragma unroll
        for (int i = 0; i < 8; ++i)
            t8[i] = fmaxf(fmaxf(st[0][i], st[0][i + 8]),
                          fmaxf(st[1][i], st[1][i + 8]));
        #pragma unroll
        for (int i = 0; i < 4; ++i) t8[i] = fmaxf(t8[i], t8[i + 4]);
        float rm = fmaxf(fmaxf(t8[0], t8[1]), fmaxf(t8[2], t8[3]));
        rm = fmaxf(rm, __shfl_xor(rm, 32, 64));

        float mn = fmaxf(m_r, rm);
        float alpha = exp2f(m_r - mn);
        m_r = mn;

        // p = exp2(s - m), in-lane sum + cross-half add
        #pragma unroll
        for (int kv2 = 0; kv2 < 2; ++kv2)
            #pragma unroll
            for (int r = 0; r < 16; ++r)
                st[kv2][r] = exp2f(st[kv2][r] - mn);
        float s8[8];
        #pragma unroll
        for (int i = 0; i < 8; ++i)
            s8[i] = (st[0][i] + st[0][i + 8]) + (st[1][i] + st[1][i + 8]);
        #pragma unroll
        for (int i = 0; i < 4; ++i) s8[i] += s8[i + 4];
        float rs = (s8[0] + s8[1]) + (s8[2] + s8[3]);
        rs += __shfl_xor(rs, 32, 64);
        l_r = l_r * alpha + rs;
        Ot[0] *= alpha;
        Ot[1] *= alpha;

        // pack P^T to bf16 pairs: pku[kv2][idx] = (p[2idx], p[2idx+1])
        unsigned pku[2][8];
        #pragma unroll
        for (int kv2 = 0; kv2 < 2; ++kv2)
            #pragma unroll
            for (int idx = 0; idx < 8; ++idx) {
                unsigned lo = __builtin_bit_cast(unsigned short, (__bf16)st[kv2][2 * idx]);
                unsigned hh = __builtin_bit_cast(unsigned short, (__bf16)st[kv2][2 * idx + 1]);
                pku[kv2][idx] = lo | (hh << 16);
            }

        // build PV B-frags: per kf, half the u32s come from the partner half
        u16x8 pb[4];
        #pragma unroll
        for (int kf = 0; kf < 4; ++kf) {
            const int kv2 = kf >> 1, base = 4 * (kf & 1);
            unsigned s0 = hi ? pku[kv2][base + 0] : pku[kv2][base + 2];
            unsigned s1 = hi ? pku[kv2][base + 1] : pku[kv2][base + 3];
            unsigned r0 = __shfl_xor(s0, 32, 64);
            unsigned r1 = __shfl_xor(s1, 32, 64);
            u32x4 w;
            w[0] = hi ? r0 : pku[kv2][base + 0];
            w[1] = hi ? r1 : pku[kv2][base + 1];
            w[2] = hi ? pku[kv2][base + 2] : r0;
            w[3] = hi ? pku[kv2][base + 3] : r1;
            pb[kf] = __builtin_bit_cast(u16x8, w);
        }

        // O^T += V^T . P^T : A = V^T rows (d), B = P^T cols (q)
        #pragma unroll
        for (int dn = 0; dn < 2; ++dn) {
            f32x16v o = Ot[dn];
            #pragma unroll
            for (int kf = 0; kf < 4; ++kf) {
                u16x8 va = *(const u16x8*)&Vlds[(dn * 32 + l31) * 72 + kf * 16 + hi * 8];
                o = mfma32(va, pb[kf], o);
            }
            Ot[dn] = o;
        }
    }

    // epilogue: normalize, write bf16 [B*T][C]; r-quads give contiguous d
    float rl = 1.0f / l_r;
    #pragma unroll
    for (int dn = 0; dn < 2; ++dn)
        #pragma unroll
        for (int rq = 0; rq < 4; ++rq) {
            u16x4 o;
            #pragma unroll
            for (int j = 0; j < 4; ++j)
                o[j] = f2bf(Ot[dn][rq * 4 + j] * rl);
            int d = dn * 32 + 8 * rq + 4 * hi;
            *(u16x4*)&aout[(b * 2048 + qg) * 1024 + h * 64 + d] = o;
        }
}

// ---------------------------------------------------------------------------
extern "C" void kernel_launch(void* const* d_in, const int* in_sizes, int n_in,
                              void* d_out, int out_size, void* d_ws, size_t ws_size,
                              hipStream_t stream)
{
    const float* x  = (const float*)d_in[0];
    const float* Wq = (const float*)d_in[1];
    const float* Wk = (const float*)d_in[2];
    const float* Wv = (const float*)d_in[3];
    const float* Wo = (const float*)d_in[4];

    unsigned short* ws = (unsigned short*)d_ws;
    unsigned short* wb = ws;                       // 4 x 1M bf16 (W^T: q,k,v,o)
    unsigned short* xb = ws + 4194304;             // 8M bf16
    unsigned short* qh = ws + 12582912;
    unsigned short* kh = qh + 8388608;
    unsigned short* vt = kh + 8388608;
    unsigned short* ao = xb;                       // alias: xb dead after QKV GEMM

    castx<<<dim3(8192), dim3(256), 0, stream>>>(x, xb);
    wtcast<<<dim3(16, 16, 4), dim3(256), 0, stream>>>(Wq, Wk, Wv, Wo, wb);
    gemm_gl<0><<<dim3(8, 64, 3), dim3(256), 0, stream>>>(xb, wb, qh, (float*)nullptr);
    attn32<<<dim3(16, 64), dim3(256), 0, stream>>>(qh, kh, vt, ao);
    gemm_gl<1><<<dim3(8, 64, 1), dim3(256), 0, stream>>>(
        ao, wb + 3 * 1048576, (unsigned short*)nullptr, (float*)d_out);
}

// Round 5
// 247.953 us; speedup vs baseline: 2.5928x; 1.2500x over previous
//
#include <hip/hip_runtime.h>
#include <hip/hip_bf16.h>

// Problem constants: B=4, T=2048, C=1024, NH=16, HD=64
#define TSEQ   2048
#define CDIM   1024
#define NHEAD  16
#define HDIM   64

typedef float f32x4  __attribute__((ext_vector_type(4)));
typedef float f32x16v __attribute__((ext_vector_type(16)));
typedef __bf16 bf16x8 __attribute__((ext_vector_type(8)));
typedef unsigned short u16x8 __attribute__((ext_vector_type(8)));
typedef unsigned short u16x4 __attribute__((ext_vector_type(4)));
typedef unsigned int   u32x4 __attribute__((ext_vector_type(4)));

#define QSCALE 0.18033688011112042f   // 0.125 * log2(e)
#define LOG2E  1.4426950408889634f

static __device__ __forceinline__ unsigned short f2bf(float f) {
    unsigned u = __builtin_bit_cast(unsigned, f);
    unsigned r = u + 0x7FFFu + ((u >> 16) & 1u);   // round-to-nearest-even
    return (unsigned short)(r >> 16);
}

static __device__ __forceinline__ f32x4 mfma16(u16x8 a, u16x8 b, f32x4 c) {
    return __builtin_amdgcn_mfma_f32_16x16x32_bf16(
        __builtin_bit_cast(bf16x8, a), __builtin_bit_cast(bf16x8, b), c, 0, 0, 0);
}
static __device__ __forceinline__ f32x16v mfma32(u16x8 a, u16x8 b, f32x16v c) {
    return __builtin_amdgcn_mfma_f32_32x32x16_bf16(
        __builtin_bit_cast(bf16x8, a), __builtin_bit_cast(bf16x8, b), c, 0, 0, 0);
}

static __device__ __forceinline__ void gload16(const void* g, void* l) {
    __builtin_amdgcn_global_load_lds(
        (const __attribute__((address_space(1))) unsigned int*)g,
        (__attribute__((address_space(3))) unsigned int*)l, 16, 0, 0);
}

// Workspace layout (u16 units):
//   wb : 0          .. 4194303   (W^T q,k,v,o bf16, 1M each -- TRANSPOSED [n][k])
//   xb : 4194304    .. 12582911  (x bf16, 8M)  -- reused as `ao` after QKV GEMM
//   qh : 12582912   .. 20971519  ([B,NH,T,HD] bf16, pre-scaled by QSCALE)
//   kh : 20971520   .. 29359103  ([B,NH,T,HD] bf16)
//   vt : 29359104   .. 37748735  ([B,NH,HD,T] bf16 -- V TRANSPOSED)

// ---------------------------------------------------------------------------
// Kernel 1a: cast x (8M f32) to bf16.
// ---------------------------------------------------------------------------
__global__ __launch_bounds__(256) void castx(
    const float* __restrict__ x, unsigned short* __restrict__ xb)
{
    int t = blockIdx.x * 256 + threadIdx.x;   // float4 index, < 2097152
    f32x4 v = *(const f32x4*)&x[t * 4];
    u16x4 o;
    o[0] = f2bf(v[0]); o[1] = f2bf(v[1]); o[2] = f2bf(v[2]); o[3] = f2bf(v[3]);
    *(u16x4*)&xb[t * 4] = o;
}

// ---------------------------------------------------------------------------
// Kernel 1b: transpose+cast the 4 weights: W [k][n] f32 -> W^T [n][k] bf16.
// ---------------------------------------------------------------------------
__global__ __launch_bounds__(256) void wtcast(
    const float* __restrict__ wq, const float* __restrict__ wk,
    const float* __restrict__ wv, const float* __restrict__ wo,
    unsigned short* __restrict__ wt)
{
    __shared__ unsigned short t[64 * 72];
    const int z = blockIdx.z;
    const float* src = (z == 0) ? wq : (z == 1) ? wk : (z == 2) ? wv : wo;
    const int k0 = blockIdx.x * 64, n0 = blockIdx.y * 64, tid = threadIdx.x;

    #pragma unroll
    for (int i = 0; i < 4; ++i) {
        int idx = i * 256 + tid;           // 0..1023
        int r = idx >> 4, c4 = idx & 15;   // r = k-row, c4 = 4-col chunk
        f32x4 v = *(const f32x4*)&src[(k0 + r) * 1024 + n0 + c4 * 4];
        u16x4 o;
        o[0] = f2bf(v[0]); o[1] = f2bf(v[1]); o[2] = f2bf(v[2]); o[3] = f2bf(v[3]);
        *(u16x4*)&t[r * 72 + c4 * 4] = o;
    }
    __syncthreads();
    #pragma unroll
    for (int i = 0; i < 2; ++i) {
        int idx = i * 256 + tid;           // 0..511
        int n = idx >> 3, k8 = idx & 7;
        u16x8 o;
        #pragma unroll
        for (int e = 0; e < 8; ++e) o[e] = t[(k8 * 8 + e) * 72 + n];
        *(u16x8*)&wt[z * 1048576 + (n0 + n) * 1024 + k0 + k8 * 8] = o;
    }
}

// ---------------------------------------------------------------------------
// Kernel 2/4: 128x128 bf16 GEMM, BK=64, m97-style global_load_lds staging.
// MODE 0: z = q/k/v. q scaled by QSCALE; v written transposed [bh][d][t].
// MODE 1: fp32 row-major to d_out.
// ---------------------------------------------------------------------------
template<int MODE>
__global__ __launch_bounds__(256) void gemm_gl(
    const unsigned short* __restrict__ A, const unsigned short* __restrict__ WT,
    unsigned short* __restrict__ outb, float* __restrict__ outf)
{
    __shared__ __align__(16) unsigned short Al[128 * 64];
    __shared__ __align__(16) unsigned short Bl[128 * 64];   // B^T tile: [n][k]

    const int tid  = threadIdx.x;
    const int z    = blockIdx.z;
    const int m0   = blockIdx.y * 128;
    const int n0   = blockIdx.x * 128;
    const unsigned short* W = WT + (MODE == 0 ? z * 1048576 : 0);

    const int wid  = tid >> 6, lane = tid & 63;
    const int wr   = (wid >> 1) * 64, wc = (wid & 1) * 64;
    const int lrow = lane & 15, lk = (lane >> 4) * 8;

    f32x4 acc[4][4] = {};

    for (int kt = 0; kt < 16; ++kt) {           // K = 1024, BK = 64
        __syncthreads();
        #pragma unroll
        for (int c = 0; c < 4; ++c) {
            int cz = wid * 4 + c;                       // 0..15
            int row = cz * 8 + (lane >> 3), col = (lane & 7) * 8;
            gload16(&A[(m0 + row) * 1024 + kt * 64 + col], &Al[cz * 512]);
            gload16(&W[(n0 + row) * 1024 + kt * 64 + col], &Bl[cz * 512]);
        }
        __syncthreads();
        #pragma unroll
        for (int ks = 0; ks < 2; ++ks) {
            u16x8 af[4], bfr[4];
            #pragma unroll
            for (int m = 0; m < 4; ++m)
                af[m] = *(const u16x8*)&Al[(wr + m * 16 + lrow) * 64 + ks * 32 + lk];
            #pragma unroll
            for (int n = 0; n < 4; ++n)
                bfr[n] = *(const u16x8*)&Bl[(wc + n * 16 + lrow) * 64 + ks * 32 + lk];
            #pragma unroll
            for (int m = 0; m < 4; ++m)
                #pragma unroll
                for (int n = 0; n < 4; ++n)
                    acc[m][n] = mfma16(af[m], bfr[n], acc[m][n]);
        }
    }

    const int g = lane >> 4;
    #pragma unroll
    for (int m = 0; m < 4; ++m)
        #pragma unroll
        for (int n = 0; n < 4; ++n)
            #pragma unroll
            for (int j = 0; j < 4; ++j) {
                int grow = m0 + wr + m * 16 + g * 4 + j;   // C/D row
                int gcol = n0 + wc + n * 16 + lrow;        // C/D col
                float val = acc[m][n][j];
                if (MODE == 0) {
                    int b = grow >> 11, t = grow & 2047;
                    int h = gcol >> 6,  d = gcol & 63;
                    if (z == 0) val *= QSCALE;             // fold attn scale into Q
                    if (z == 2)   // V: store transposed [bh][d][t]
                        outb[z * 8388608 + (((b << 4) + h) * 64 + d) * 2048 + t] = f2bf(val);
                    else
                        outb[z * 8388608 + (((b << 4) + h) * 2048 + t) * 64 + d] = f2bf(val);
                } else {
                    outf[grow * 1024 + gcol] = val;
                }
            }
}

// ---------------------------------------------------------------------------
// Kernel 3: pipelined flash attention, 32x32 MFMA, swapped QK^T.
// Grid (8 q-block-pairs, 64 b*h): block j handles q-blocks (15-j) then (j)
// -> uniform 34 KV tiles/block. Double-buffered K/V LDS, one barrier/tile,
// next tile's global loads issued before compute (latency hidden).
// ---------------------------------------------------------------------------
__global__ __launch_bounds__(256) void attn32p(
    const unsigned short* __restrict__ qh, const unsigned short* __restrict__ kh,
    const unsigned short* __restrict__ vt, unsigned short* __restrict__ aout)
{
    __shared__ __align__(16) unsigned short Kl[2][64 * 72];
    __shared__ __align__(16) unsigned short Vl[2][64 * 72];   // V^T tiles: [d][kv]

    const int j   = blockIdx.x;            // 0..7
    const int bh  = blockIdx.y;
    const int h   = bh & 15, b = bh >> 4;
    const int tid = threadIdx.x, wid = tid >> 6, lane = tid & 63;
    const int l31 = lane & 31, hi = lane >> 5;

    const int blkA = 15 - j, blkB = j;
    const int ntA  = 2 * blkA + 2;         // tiles for q-block A
    const int nt   = 34;                   // ntA + ntB (uniform)

    const unsigned short* Qb = qh + bh * (TSEQ * HDIM);
    const unsigned short* Kb = kh + bh * (TSEQ * HDIM);
    const unsigned short* Vb = vt + bh * (TSEQ * HDIM);  // [d][t]

    const float slope2 = exp2f(-0.5f * (float)(h + 1)) * LOG2E;

    // per-q-block state (starts on block A)
    int qw = blkA * 128 + wid * 32;        // wave's first q row
    int qg = qw + l31;                     // lane's q row
    u16x8 qf[4];                           // Q B-frags (Q pre-scaled by QSCALE)
    #pragma unroll
    for (int kf = 0; kf < 4; ++kf)
        qf[kf] = *(const u16x8*)&Qb[qg * 64 + kf * 16 + hi * 8];
    float m_r = -1e30f, l_r = 0.f;
    f32x16v Ot[2] = {};                    // O^T: d = dn*32+(r&3)+8*(r>>2)+4*hi

    // prologue: stage tile 0 (kv0=0 of block A) into buffer 0
    #pragma unroll
    for (int i = 0; i < 2; ++i) {
        int idx = i * 256 + tid, row = idx >> 3, c8 = idx & 7;
        *(u16x8*)&Kl[0][row * 72 + c8 * 8] = *(const u16x8*)&Kb[row * 64 + c8 * 8];
        *(u16x8*)&Vl[0][row * 72 + c8 * 8] = *(const u16x8*)&Vb[row * 2048 + c8 * 8];
    }
    int cur = 0;

    for (int t = 0; t < nt; ++t) {
        const int kv0 = (t < ntA ? t : t - ntA) * 64;
        __syncthreads();                   // buf[cur] ready; prev reads done

        // issue next tile's global loads (latency hides under compute)
        u16x8 kreg[2], vreg[2];
        const bool pre = (t + 1 < nt);
        if (pre) {
            const int t1 = t + 1;
            const int kv0n = (t1 < ntA ? t1 : t1 - ntA) * 64;
            #pragma unroll
            for (int i = 0; i < 2; ++i) {
                int idx = i * 256 + tid, row = idx >> 3, c8 = idx & 7;
                kreg[i] = *(const u16x8*)&Kb[(kv0n + row) * 64 + c8 * 8];
                vreg[i] = *(const u16x8*)&Vb[row * 2048 + kv0n + c8 * 8];
            }
        }

        if (kv0 <= qw + 31) {              // wave-uniform: any unmasked rows?
            // S^T = K . Q : 2 kv-frags x 4 k-frags
            f32x16v st[2];
            __builtin_amdgcn_s_setprio(1);
            #pragma unroll
            for (int kv2 = 0; kv2 < 2; ++kv2) {
                f32x16v a = {};
                #pragma unroll
                for (int kf = 0; kf < 4; ++kf) {
                    u16x8 ka = *(const u16x8*)&Kl[cur][(kv2 * 32 + l31) * 72 + kf * 16 + hi * 8];
                    a = mfma32(ka, qf[kf], a);
                }
                st[kv2] = a;
            }
            __builtin_amdgcn_s_setprio(0);

            // bias (+ causal mask on diagonal tiles); exp2 domain
            const bool diag = (kv0 + 63 > qw);
            #pragma unroll
            for (int kv2 = 0; kv2 < 2; ++kv2) {
                float base = slope2 * (float)(kv0 + kv2 * 32 + 4 * hi - 2047);
                #pragma unroll
                for (int r = 0; r < 16; ++r) {
                    int koff = (r & 3) + 8 * (r >> 2);
                    float v = st[kv2][r] + fmaf(slope2, (float)koff, base);
                    if (diag) {
                        int kv = kv0 + kv2 * 32 + koff + 4 * hi;
                        if (kv > qg) v = -1e30f;
                    }
                    st[kv2][r] = v;
                }
            }

            // row max: in-lane tree + one cross-half swap
            float t8[8];
            #pragma unroll
            for (int i = 0; i < 8; ++i)
                t8[i] = fmaxf(fmaxf(st[0][i], st[0][i + 8]),
                              fmaxf(st[1][i], st[1][i + 8]));
            #pragma unroll
            for (int i = 0; i < 4; ++i) t8[i] = fmaxf(t8[i], t8[i + 4]);
            float rm = fmaxf(fmaxf(t8[0], t8[1]), fmaxf(t8[2], t8[3]));
            rm = fmaxf(rm, __shfl_xor(rm, 32, 64));

            float mn = fmaxf(m_r, rm);
            float alpha = exp2f(m_r - mn);
            m_r = mn;

            #pragma unroll
            for (int kv2 = 0; kv2 < 2; ++kv2)
                #pragma unroll
                for (int r = 0; r < 16; ++r)
                    st[kv2][r] = exp2f(st[kv2][r] - mn);
            float s8[8];
            #pragma unroll
            for (int i = 0; i < 8; ++i)
                s8[i] = (st[0][i] + st[0][i + 8]) + (st[1][i] + st[1][i + 8]);
            #pragma unroll
            for (int i = 0; i < 4; ++i) s8[i] += s8[i + 4];
            float rs = (s8[0] + s8[1]) + (s8[2] + s8[3]);
            rs += __shfl_xor(rs, 32, 64);
            l_r = l_r * alpha + rs;
            Ot[0] *= alpha;
            Ot[1] *= alpha;

            // pack P^T to bf16 pairs
            unsigned pku[2][8];
            #pragma unroll
            for (int kv2 = 0; kv2 < 2; ++kv2)
                #pragma unroll
                for (int idx = 0; idx < 8; ++idx) {
                    unsigned lo = __builtin_bit_cast(unsigned short, (__bf16)st[kv2][2 * idx]);
                    unsigned hh = __builtin_bit_cast(unsigned short, (__bf16)st[kv2][2 * idx + 1]);
                    pku[kv2][idx] = lo | (hh << 16);
                }

            // build PV B-frags: half the u32s come from the partner half-wave
            u16x8 pb[4];
            #pragma unroll
            for (int kf = 0; kf < 4; ++kf) {
                const int kv2 = kf >> 1, base = 4 * (kf & 1);
                unsigned s0 = hi ? pku[kv2][base + 0] : pku[kv2][base + 2];
                unsigned s1 = hi ? pku[kv2][base + 1] : pku[kv2][base + 3];
                unsigned r0 = __shfl_xor(s0, 32, 64);
                unsigned r1 = __shfl_xor(s1, 32, 64);
                u32x4 w;
                w[0] = hi ? r0 : pku[kv2][base + 0];
                w[1] = hi ? r1 : pku[kv2][base + 1];
                w[2] = hi ? pku[kv2][base + 2] : r0;
                w[3] = hi ? pku[kv2][base + 3] : r1;
                pb[kf] = __builtin_bit_cast(u16x8, w);
            }

            // O^T += V^T . P^T
            __builtin_amdgcn_s_setprio(1);
            #pragma unroll
            for (int dn = 0; dn < 2; ++dn) {
                f32x16v o = Ot[dn];
                #pragma unroll
                for (int kf = 0; kf < 4; ++kf) {
                    u16x8 va = *(const u16x8*)&Vl[cur][(dn * 32 + l31) * 72 + kf * 16 + hi * 8];
                    o = mfma32(va, pb[kf], o);
                }
                Ot[dn] = o;
            }
            __builtin_amdgcn_s_setprio(0);
        }

        // boundary: finish q-block A, switch state to q-block B
        if (t == ntA - 1) {
            float rl = 1.0f / l_r;
            #pragma unroll
            for (int dn = 0; dn < 2; ++dn)
                #pragma unroll
                for (int rq = 0; rq < 4; ++rq) {
                    u16x4 o;
                    #pragma unroll
                    for (int jj = 0; jj < 4; ++jj)
                        o[jj] = f2bf(Ot[dn][rq * 4 + jj] * rl);
                    int d = dn * 32 + 8 * rq + 4 * hi;
                    *(u16x4*)&aout[(b * 2048 + qg) * 1024 + h * 64 + d] = o;
                }
            qw = blkB * 128 + wid * 32;
            qg = qw + l31;
            #pragma unroll
            for (int kf = 0; kf < 4; ++kf)
                qf[kf] = *(const u16x8*)&Qb[qg * 64 + kf * 16 + hi * 8];
            m_r = -1e30f; l_r = 0.f;
            Ot[0] = (f32x16v){};
            Ot[1] = (f32x16v){};
        }

        // write prefetched tile into the other buffer (readers blocked by
        // next iteration's barrier; current readers use buf[cur])
        if (pre) {
            #pragma unroll
            for (int i = 0; i < 2; ++i) {
                int idx = i * 256 + tid, row = idx >> 3, c8 = idx & 7;
                *(u16x8*)&Kl[cur ^ 1][row * 72 + c8 * 8] = kreg[i];
                *(u16x8*)&Vl[cur ^ 1][row * 72 + c8 * 8] = vreg[i];
            }
        }
        cur ^= 1;
    }

    // final epilogue (q-block B)
    float rl = 1.0f / l_r;
    #pragma unroll
    for (int dn = 0; dn < 2; ++dn)
        #pragma unroll
        for (int rq = 0; rq < 4; ++rq) {
            u16x4 o;
            #pragma unroll
            for (int jj = 0; jj < 4; ++jj)
                o[jj] = f2bf(Ot[dn][rq * 4 + jj] * rl);
            int d = dn * 32 + 8 * rq + 4 * hi;
            *(u16x4*)&aout[(b * 2048 + qg) * 1024 + h * 64 + d] = o;
        }
}

// ---------------------------------------------------------------------------
extern "C" void kernel_launch(void* const* d_in, const int* in_sizes, int n_in,
                              void* d_out, int out_size, void* d_ws, size_t ws_size,
                              hipStream_t stream)
{
    const float* x  = (const float*)d_in[0];
    const float* Wq = (const float*)d_in[1];
    const float* Wk = (const float*)d_in[2];
    const float* Wv = (const float*)d_in[3];
    const float* Wo = (const float*)d_in[4];

    unsigned short* ws = (unsigned short*)d_ws;
    unsigned short* wb = ws;                       // 4 x 1M bf16 (W^T: q,k,v,o)
    unsigned short* xb = ws + 4194304;             // 8M bf16
    unsigned short* qh = ws + 12582912;
    unsigned short* kh = qh + 8388608;
    unsigned short* vt = kh + 8388608;
    unsigned short* ao = xb;                       // alias: xb dead after QKV GEMM

    castx<<<dim3(8192), dim3(256), 0, stream>>>(x, xb);
    wtcast<<<dim3(16, 16, 4), dim3(256), 0, stream>>>(Wq, Wk, Wv, Wo, wb);
    gemm_gl<0><<<dim3(8, 64, 3), dim3(256), 0, stream>>>(xb, wb, qh, (float*)nullptr);
    attn32p<<<dim3(8, 64), dim3(256), 0, stream>>>(qh, kh, vt, ao);
    gemm_gl<1><<<dim3(8, 64, 1), dim3(256), 0, stream>>>(
        ao, wb + 3 * 1048576, (unsigned short*)nullptr, (float*)d_out);
}

// Round 6
// 238.647 us; speedup vs baseline: 2.6939x; 1.0390x over previous
//
#include <hip/hip_runtime.h>
#include <hip/hip_bf16.h>

// Problem constants: B=4, T=2048, C=1024, NH=16, HD=64
#define TSEQ   2048
#define CDIM   1024
#define NHEAD  16
#define HDIM   64

typedef float f32x4  __attribute__((ext_vector_type(4)));
typedef float f32x16v __attribute__((ext_vector_type(16)));
typedef __bf16 bf16x8 __attribute__((ext_vector_type(8)));
typedef unsigned short u16x8 __attribute__((ext_vector_type(8)));
typedef unsigned short u16x4 __attribute__((ext_vector_type(4)));
typedef unsigned int   u32x4 __attribute__((ext_vector_type(4)));

#define QSCALE 0.18033688011112042f   // 0.125 * log2(e)
#define LOG2E  1.4426950408889634f

static __device__ __forceinline__ unsigned short f2bf(float f) {
    unsigned u = __builtin_bit_cast(unsigned, f);
    unsigned r = u + 0x7FFFu + ((u >> 16) & 1u);   // round-to-nearest-even
    return (unsigned short)(r >> 16);
}

static __device__ __forceinline__ f32x4 mfma16(u16x8 a, u16x8 b, f32x4 c) {
    return __builtin_amdgcn_mfma_f32_16x16x32_bf16(
        __builtin_bit_cast(bf16x8, a), __builtin_bit_cast(bf16x8, b), c, 0, 0, 0);
}
static __device__ __forceinline__ f32x16v mfma32(u16x8 a, u16x8 b, f32x16v c) {
    return __builtin_amdgcn_mfma_f32_32x32x16_bf16(
        __builtin_bit_cast(bf16x8, a), __builtin_bit_cast(bf16x8, b), c, 0, 0, 0);
}

static __device__ __forceinline__ void gload16(const void* g, void* l) {
    __builtin_amdgcn_global_load_lds(
        (const __attribute__((address_space(1))) unsigned int*)g,
        (__attribute__((address_space(3))) unsigned int*)l, 16, 0, 0);
}

// Workspace layout (u16 units):
//   wb : 0          .. 4194303   (W^T q,k,v,o bf16, 1M each -- TRANSPOSED [n][k])
//   xb : 4194304    .. 12582911  (x bf16, 8M)  -- reused as `ao` after QKV GEMM
//   qh : 12582912   .. 20971519  ([B,NH,T,HD] bf16, pre-scaled by QSCALE)
//   kh : 20971520   .. 29359103  ([B,NH,T,HD] bf16)
//   vt : 29359104   .. 37748735  ([B,NH,HD,T] bf16 -- V TRANSPOSED)

// ---------------------------------------------------------------------------
// Kernel 1a: cast x (8M f32) to bf16.
// ---------------------------------------------------------------------------
__global__ __launch_bounds__(256) void castx(
    const float* __restrict__ x, unsigned short* __restrict__ xb)
{
    int t = blockIdx.x * 256 + threadIdx.x;   // float4 index, < 2097152
    f32x4 v = *(const f32x4*)&x[t * 4];
    u16x4 o;
    o[0] = f2bf(v[0]); o[1] = f2bf(v[1]); o[2] = f2bf(v[2]); o[3] = f2bf(v[3]);
    *(u16x4*)&xb[t * 4] = o;
}

// ---------------------------------------------------------------------------
// Kernel 1b: transpose+cast the 4 weights: W [k][n] f32 -> W^T [n][k] bf16.
// ---------------------------------------------------------------------------
__global__ __launch_bounds__(256) void wtcast(
    const float* __restrict__ wq, const float* __restrict__ wk,
    const float* __restrict__ wv, const float* __restrict__ wo,
    unsigned short* __restrict__ wt)
{
    __shared__ unsigned short t[64 * 72];
    const int z = blockIdx.z;
    const float* src = (z == 0) ? wq : (z == 1) ? wk : (z == 2) ? wv : wo;
    const int k0 = blockIdx.x * 64, n0 = blockIdx.y * 64, tid = threadIdx.x;

    #pragma unroll
    for (int i = 0; i < 4; ++i) {
        int idx = i * 256 + tid;           // 0..1023
        int r = idx >> 4, c4 = idx & 15;   // r = k-row, c4 = 4-col chunk
        f32x4 v = *(const f32x4*)&src[(k0 + r) * 1024 + n0 + c4 * 4];
        u16x4 o;
        o[0] = f2bf(v[0]); o[1] = f2bf(v[1]); o[2] = f2bf(v[2]); o[3] = f2bf(v[3]);
        *(u16x4*)&t[r * 72 + c4 * 4] = o;
    }
    __syncthreads();
    #pragma unroll
    for (int i = 0; i < 2; ++i) {
        int idx = i * 256 + tid;           // 0..511
        int n = idx >> 3, k8 = idx & 7;
        u16x8 o;
        #pragma unroll
        for (int e = 0; e < 8; ++e) o[e] = t[(k8 * 8 + e) * 72 + n];
        *(u16x8*)&wt[z * 1048576 + (n0 + n) * 1024 + k0 + k8 * 8] = o;
    }
}

// ---------------------------------------------------------------------------
// Kernel 2/4: 128x128 bf16 GEMM, BK=64, m97-style global_load_lds staging.
// MODE 0: z = q/k/v. q scaled by QSCALE; v written transposed [bh][d][t].
// MODE 1: fp32 row-major to d_out.
// ---------------------------------------------------------------------------
template<int MODE>
__global__ __launch_bounds__(256) void gemm_gl(
    const unsigned short* __restrict__ A, const unsigned short* __restrict__ WT,
    unsigned short* __restrict__ outb, float* __restrict__ outf)
{
    __shared__ __align__(16) unsigned short Al[128 * 64];
    __shared__ __align__(16) unsigned short Bl[128 * 64];   // B^T tile: [n][k]

    const int tid  = threadIdx.x;
    const int z    = blockIdx.z;
    const int m0   = blockIdx.y * 128;
    const int n0   = blockIdx.x * 128;
    const unsigned short* W = WT + (MODE == 0 ? z * 1048576 : 0);

    const int wid  = tid >> 6, lane = tid & 63;
    const int wr   = (wid >> 1) * 64, wc = (wid & 1) * 64;
    const int lrow = lane & 15, lk = (lane >> 4) * 8;

    f32x4 acc[4][4] = {};

    for (int kt = 0; kt < 16; ++kt) {           // K = 1024, BK = 64
        __syncthreads();
        #pragma unroll
        for (int c = 0; c < 4; ++c) {
            int cz = wid * 4 + c;                       // 0..15
            int row = cz * 8 + (lane >> 3), col = (lane & 7) * 8;
            gload16(&A[(m0 + row) * 1024 + kt * 64 + col], &Al[cz * 512]);
            gload16(&W[(n0 + row) * 1024 + kt * 64 + col], &Bl[cz * 512]);
        }
        __syncthreads();
        #pragma unroll
        for (int ks = 0; ks < 2; ++ks) {
            u16x8 af[4], bfr[4];
            #pragma unroll
            for (int m = 0; m < 4; ++m)
                af[m] = *(const u16x8*)&Al[(wr + m * 16 + lrow) * 64 + ks * 32 + lk];
            #pragma unroll
            for (int n = 0; n < 4; ++n)
                bfr[n] = *(const u16x8*)&Bl[(wc + n * 16 + lrow) * 64 + ks * 32 + lk];
            #pragma unroll
            for (int m = 0; m < 4; ++m)
                #pragma unroll
                for (int n = 0; n < 4; ++n)
                    acc[m][n] = mfma16(af[m], bfr[n], acc[m][n]);
        }
    }

    const int g = lane >> 4;
    #pragma unroll
    for (int m = 0; m < 4; ++m)
        #pragma unroll
        for (int n = 0; n < 4; ++n)
            #pragma unroll
            for (int j = 0; j < 4; ++j) {
                int grow = m0 + wr + m * 16 + g * 4 + j;   // C/D row
                int gcol = n0 + wc + n * 16 + lrow;        // C/D col
                float val = acc[m][n][j];
                if (MODE == 0) {
                    int b = grow >> 11, t = grow & 2047;
                    int h = gcol >> 6,  d = gcol & 63;
                    if (z == 0) val *= QSCALE;             // fold attn scale into Q
                    if (z == 2)   // V: store transposed [bh][d][t]
                        outb[z * 8388608 + (((b << 4) + h) * 64 + d) * 2048 + t] = f2bf(val);
                    else
                        outb[z * 8388608 + (((b << 4) + h) * 2048 + t) * 64 + d] = f2bf(val);
                } else {
                    outf[grow * 1024 + gcol] = val;
                }
            }
}

// ---------------------------------------------------------------------------
// Kernel 3: pipelined flash attention, KVBLK=128, swapped QK^T (32x32 MFMA),
// global_load_lds staging with XOR-swizzled source (linear LDS dest), one
// barrier per 128-kv tile, defer-max rescale.
// Grid (8 pairs, 64 b*h): block j does q-blocks (15-j) then (j): 17 tiles.
// K LDS tile [128 kv][64 d] (chunk swz c^(kv&7)); V^T tile [64 d][128 kv]
// (chunk swz c^(d&15)).
// ---------------------------------------------------------------------------
__global__ __launch_bounds__(256) void attn128(
    const unsigned short* __restrict__ qh, const unsigned short* __restrict__ kh,
    const unsigned short* __restrict__ vt, unsigned short* __restrict__ aout)
{
    __shared__ __align__(16) unsigned short Kl[2][128 * 64];
    __shared__ __align__(16) unsigned short Vl[2][64 * 128];

    const int j   = blockIdx.x;            // 0..7
    const int bh  = blockIdx.y;
    const int h   = bh & 15, b = bh >> 4;
    const int tid = threadIdx.x, wid = tid >> 6, lane = tid & 63;
    const int l31 = lane & 31, hi = lane >> 5;

    const int blkA = 15 - j, blkB = j;
    const int ntA  = blkA + 1;             // 128-kv tiles for q-block A
    const int nt   = 17;                   // ntA + ntB (uniform)

    const unsigned short* Qb = qh + bh * (TSEQ * HDIM);
    const unsigned short* Kb = kh + bh * (TSEQ * HDIM);
    const unsigned short* Vb = vt + bh * (TSEQ * HDIM);  // [d][t]

    const float slope2 = exp2f(-0.5f * (float)(h + 1)) * LOG2E;

    // staging lane constants (source-side XOR swizzle, LDS dest linear)
    const int krow = lane >> 3;                  // K: row-in-8-row-group
    const int kgc  = (lane & 7) ^ krow;          // K: swizzled global chunk
    const int vrow = lane >> 4;                  // V: row-in-4-row-group
    const int vcc  = lane & 15;

#define STAGE(BUF, KV) do {                                                   \
    _Pragma("unroll")                                                         \
    for (int i_ = 0; i_ < 4; ++i_) {                                          \
        int g_ = wid * 4 + i_;                                                \
        gload16(&Kb[((KV) + g_ * 8 + krow) * 64 + kgc * 8],                   \
                &Kl[BUF][g_ * 512]);                                          \
        int d_ = g_ * 4 + vrow;                                               \
        int gc_ = vcc ^ (d_ & 15);                                            \
        gload16(&Vb[d_ * 2048 + (KV) + gc_ * 8], &Vl[BUF][g_ * 512]);         \
    } } while (0)

    // per-q-block state (starts on block A)
    int qw = blkA * 128 + wid * 32;        // wave's first q row
    int qg = qw + l31;                     // lane's q row
    u16x8 qf[4];                           // Q B-frags (pre-scaled by QSCALE)
    #pragma unroll
    for (int kf = 0; kf < 4; ++kf)
        qf[kf] = *(const u16x8*)&Qb[qg * 64 + kf * 16 + hi * 8];
    float m_r = -1e30f, l_r = 0.f;
    f32x16v Ot[2] = {};                    // O^T: d = dn*32+(r&3)+8*(r>>2)+4*hi

    STAGE(0, 0);                           // prologue: tile 0 -> buf 0
    int cur = 0;

    for (int t = 0; t < nt; ++t) {
        const int kv0 = (t < ntA ? t : t - ntA) * 128;
        __syncthreads();                   // drains this tile's loads (vmcnt 0)

        if (t + 1 < nt) {                  // issue next tile's loads
            const int t1 = t + 1;
            const int kv0n = (t1 < ntA ? t1 : t1 - ntA) * 128;
            STAGE(cur ^ 1, kv0n);
        }

        // S^T = K . Q : 4 kv-frags x 4 k-frags
        f32x16v st[4];
        __builtin_amdgcn_s_setprio(1);
        #pragma unroll
        for (int kv2 = 0; kv2 < 4; ++kv2) {
            f32x16v a = {};
            #pragma unroll
            for (int kf = 0; kf < 4; ++kf) {
                u16x8 ka = *(const u16x8*)&Kl[cur][(kv2 * 32 + l31) * 64 +
                                                   (((kf * 2 + hi) ^ (l31 & 7)) * 8)];
                a = mfma32(ka, qf[kf], a);
            }
            st[kv2] = a;
        }
        __builtin_amdgcn_s_setprio(0);

        // bias (+ causal mask on the diagonal tile); exp2 domain
        const bool diag = (kv0 + 127 > qw);
        #pragma unroll
        for (int kv2 = 0; kv2 < 4; ++kv2) {
            float base = slope2 * (float)(kv0 + kv2 * 32 + 4 * hi - 2047);
            #pragma unroll
            for (int r = 0; r < 16; ++r) {
                int koff = (r & 3) + 8 * (r >> 2);
                float v = st[kv2][r] + fmaf(slope2, (float)koff, base);
                if (diag) {
                    int kv = kv0 + kv2 * 32 + koff + 4 * hi;
                    if (kv > qg) v = -1e30f;
                }
                st[kv2][r] = v;
            }
        }

        // row max: in-lane tree + one cross-half swap
        float t16[16];
        #pragma unroll
        for (int i = 0; i < 16; ++i)
            t16[i] = fmaxf(fmaxf(st[0][i], st[1][i]), fmaxf(st[2][i], st[3][i]));
        #pragma unroll
        for (int i = 0; i < 8; ++i) t16[i] = fmaxf(t16[i], t16[i + 8]);
        #pragma unroll
        for (int i = 0; i < 4; ++i) t16[i] = fmaxf(t16[i], t16[i + 4]);
        float rm = fmaxf(fmaxf(t16[0], t16[1]), fmaxf(t16[2], t16[3]));
        rm = fmaxf(rm, __shfl_xor(rm, 32, 64));

        // defer-max: rescale only when the max moved by > 8 (exp2 domain)
        if (!__all(rm - m_r <= 8.0f)) {
            float mn = fmaxf(m_r, rm);
            float alpha = exp2f(m_r - mn);
            m_r = mn;
            l_r *= alpha;
            Ot[0] *= alpha;
            Ot[1] *= alpha;
        }

        // p = exp2(s - m); in-lane sum + cross-half add
        #pragma unroll
        for (int kv2 = 0; kv2 < 4; ++kv2)
            #pragma unroll
            for (int r = 0; r < 16; ++r)
                st[kv2][r] = exp2f(st[kv2][r] - m_r);
        float s16[16];
        #pragma unroll
        for (int i = 0; i < 16; ++i)
            s16[i] = (st[0][i] + st[1][i]) + (st[2][i] + st[3][i]);
        #pragma unroll
        for (int i = 0; i < 8; ++i) s16[i] += s16[i + 8];
        #pragma unroll
        for (int i = 0; i < 4; ++i) s16[i] += s16[i + 4];
        float rs = (s16[0] + s16[1]) + (s16[2] + s16[3]);
        rs += __shfl_xor(rs, 32, 64);
        l_r += rs;

        // pack P^T to bf16 pairs
        unsigned pku[4][8];
        #pragma unroll
        for (int kv2 = 0; kv2 < 4; ++kv2)
            #pragma unroll
            for (int idx = 0; idx < 8; ++idx) {
                unsigned lo = __builtin_bit_cast(unsigned short, (__bf16)st[kv2][2 * idx]);
                unsigned hh = __builtin_bit_cast(unsigned short, (__bf16)st[kv2][2 * idx + 1]);
                pku[kv2][idx] = lo | (hh << 16);
            }

        // build PV B-frags: half the u32s come from the partner half-wave
        u16x8 pb[8];
        #pragma unroll
        for (int kf = 0; kf < 8; ++kf) {
            const int kv2 = kf >> 1, base = 4 * (kf & 1);
            unsigned s0 = hi ? pku[kv2][base + 0] : pku[kv2][base + 2];
            unsigned s1 = hi ? pku[kv2][base + 1] : pku[kv2][base + 3];
            unsigned r0 = __shfl_xor(s0, 32, 64);
            unsigned r1 = __shfl_xor(s1, 32, 64);
            u32x4 w;
            w[0] = hi ? r0 : pku[kv2][base + 0];
            w[1] = hi ? r1 : pku[kv2][base + 1];
            w[2] = hi ? pku[kv2][base + 2] : r0;
            w[3] = hi ? pku[kv2][base + 3] : r1;
            pb[kf] = __builtin_bit_cast(u16x8, w);
        }

        // O^T += V^T . P^T
        __builtin_amdgcn_s_setprio(1);
        #pragma unroll
        for (int dn = 0; dn < 2; ++dn) {
            f32x16v o = Ot[dn];
            #pragma unroll
            for (int kf = 0; kf < 8; ++kf) {
                u16x8 va = *(const u16x8*)&Vl[cur][(dn * 32 + l31) * 128 +
                                                   (((kf * 2 + hi) ^ (l31 & 15)) * 8)];
                o = mfma32(va, pb[kf], o);
            }
            Ot[dn] = o;
        }
        __builtin_amdgcn_s_setprio(0);

        // boundary: finish q-block A, switch state to q-block B
        if (t == ntA - 1) {
            float rl = 1.0f / l_r;
            #pragma unroll
            for (int dn = 0; dn < 2; ++dn)
                #pragma unroll
                for (int rq = 0; rq < 4; ++rq) {
                    u16x4 o;
                    #pragma unroll
                    for (int jj = 0; jj < 4; ++jj)
                        o[jj] = f2bf(Ot[dn][rq * 4 + jj] * rl);
                    int d = dn * 32 + 8 * rq + 4 * hi;
                    *(u16x4*)&aout[(b * 2048 + qg) * 1024 + h * 64 + d] = o;
                }
            qw = blkB * 128 + wid * 32;
            qg = qw + l31;
            #pragma unroll
            for (int kf = 0; kf < 4; ++kf)
                qf[kf] = *(const u16x8*)&Qb[qg * 64 + kf * 16 + hi * 8];
            m_r = -1e30f; l_r = 0.f;
            Ot[0] = (f32x16v){};
            Ot[1] = (f32x16v){};
        }

        cur ^= 1;
    }

    // final epilogue (q-block B)
    float rl = 1.0f / l_r;
    #pragma unroll
    for (int dn = 0; dn < 2; ++dn)
        #pragma unroll
        for (int rq = 0; rq < 4; ++rq) {
            u16x4 o;
            #pragma unroll
            for (int jj = 0; jj < 4; ++jj)
                o[jj] = f2bf(Ot[dn][rq * 4 + jj] * rl);
            int d = dn * 32 + 8 * rq + 4 * hi;
            *(u16x4*)&aout[(b * 2048 + qg) * 1024 + h * 64 + d] = o;
        }
#undef STAGE
}

// ---------------------------------------------------------------------------
extern "C" void kernel_launch(void* const* d_in, const int* in_sizes, int n_in,
                              void* d_out, int out_size, void* d_ws, size_t ws_size,
                              hipStream_t stream)
{
    const float* x  = (const float*)d_in[0];
    const float* Wq = (const float*)d_in[1];
    const float* Wk = (const float*)d_in[2];
    const float* Wv = (const float*)d_in[3];
    const float* Wo = (const float*)d_in[4];

    unsigned short* ws = (unsigned short*)d_ws;
    unsigned short* wb = ws;                       // 4 x 1M bf16 (W^T: q,k,v,o)
    unsigned short* xb = ws + 4194304;             // 8M bf16
    unsigned short* qh = ws + 12582912;
    unsigned short* kh = qh + 8388608;
    unsigned short* vt = kh + 8388608;
    unsigned short* ao = xb;                       // alias: xb dead after QKV GEMM

    castx<<<dim3(8192), dim3(256), 0, stream>>>(x, xb);
    wtcast<<<dim3(16, 16, 4), dim3(256), 0, stream>>>(Wq, Wk, Wv, Wo, wb);
    gemm_gl<0><<<dim3(8, 64, 3), dim3(256), 0, stream>>>(xb, wb, qh, (float*)nullptr);
    attn128<<<dim3(8, 64), dim3(256), 0, stream>>>(qh, kh, vt, ao);
    gemm_gl<1><<<dim3(8, 64, 1), dim3(256), 0, stream>>>(
        ao, wb + 3 * 1048576, (unsigned short*)nullptr, (float*)d_out);
}